// Round 9
// baseline (251.605 us; speedup 1.0000x reference)
//
#include <hip/hip_runtime.h>

#define NRAYS 16384
#define NLEV  16
#define THASH 524288
#define MAXACT 48
#define MAXPTS (NRAYS*MAXACT)
#define MBLK  256      // 4 waves/block
#define MGRID 1024
#define STR   68       // floats per point-row: 272B = 17*16B -> float4-aligned, 2-way banks

// fp32 z_i exactly as np.linspace(2,6,128) fp32
__device__ __forceinline__ float zval32(int i) {
  const float step = 4.0f / 127.0f;
  return __fadd_rn(2.0f, __fmul_rn((float)i, step));
}
__device__ __forceinline__ float pcoord(float o, float d, float z) {
  return __fadd_rn(o, __fmul_rn(d, z));
}

// ---------------- kernel 1: classify rays, SH encode, compact ----------------
__global__ __launch_bounds__(64)
void k_classify(const float* __restrict__ rays,
                float* __restrict__ sh,
                unsigned* __restrict__ counter,
                unsigned* __restrict__ rbase,
                unsigned* __restrict__ rn,
                unsigned* __restrict__ plist) {
  int lane = threadIdx.x;
  int r = blockIdx.x * 64 + lane;
  if (r >= NRAYS) return;
  float ox = rays[6*r+0], oy = rays[6*r+1], oz = rays[6*r+2];
  float dx = rays[6*r+3], dy = rays[6*r+4], dz = rays[6*r+5];
  float x = dx, y = dy, z = dz;
  float xx = x*x, yy = y*y, zz = z*z, xy = x*y, yz = y*z, xz = x*z;
  float* shp = sh + 16*r;
  shp[0]  = 0.28209479177387814f;
  shp[1]  = -0.4886025119029199f * y;
  shp[2]  =  0.4886025119029199f * z;
  shp[3]  = -0.4886025119029199f * x;
  shp[4]  =  1.0925484305920792f * xy;
  shp[5]  = -1.0925484305920792f * yz;
  shp[6]  =  0.31539156525252005f * (2.0f*zz - xx - yy);
  shp[7]  = -1.0925484305920792f * xz;
  shp[8]  =  0.5462742152960396f * (xx - yy);
  shp[9]  = -0.5900435899266435f * y * (3.0f*xx - yy);
  shp[10] =  2.890611442640554f  * xy * z;
  shp[11] = -0.4570457994644658f * y * (4.0f*zz - xx - yy);
  shp[12] =  0.3731763325901154f * z * (2.0f*zz - 3.0f*xx - 3.0f*yy);
  shp[13] = -0.4570457994644658f * x * (4.0f*zz - xx - yy);
  shp[14] =  1.445305721320277f  * z * (xx - yy);
  shp[15] = -0.5900435899266435f * x * (xx - 3.0f*yy);
  unsigned n = 0;
  for (int i = 0; i < 128; ++i) {
    float zi = zval32(i);
    float px = pcoord(ox, dx, zi);
    float py = pcoord(oy, dy, zi);
    float pz = pcoord(oz, dz, zi);
    bool in = (px >= -1.5f) && (px <= 1.5f) && (py >= -1.5f) && (py <= 1.5f)
           && (pz >= -1.5f) && (pz <= 1.5f);
    if (!in) break;
    ++n;
  }
  unsigned pre = n;
#pragma unroll
  for (int d = 1; d < 64; d <<= 1) {
    unsigned v = __shfl_up(pre, d, 64);
    if (lane >= d) pre += v;
  }
  unsigned excl  = pre - n;
  unsigned total = __shfl(pre, 63, 64);
  unsigned base0 = 0;
  if (lane == 0) base0 = atomicAdd(counter, total);
  base0 = __shfl(base0, 0, 64);
  unsigned base = base0 + excl;
  rbase[r] = base;
  rn[r]    = n;
  for (unsigned i = 0; i < n; ++i) plist[base + i] = (unsigned)(r*128 + (int)i);
}

// ---------------- k_mlp layer helpers ----------------
// acc order: k ascending per (j,point) -> bit-identical to validated kernels.
#define FMAC16(a_, Wp_)                                                     \
  { const float4* __restrict__ Wk = (const float4*)(Wp_);                   \
    float4 w0 = Wk[0], w1 = Wk[1], w2 = Wk[2], w3 = Wk[3];                  \
    acc[ 0]=fmaf(a_,w0.x,acc[ 0]); acc[ 1]=fmaf(a_,w0.y,acc[ 1]);           \
    acc[ 2]=fmaf(a_,w0.z,acc[ 2]); acc[ 3]=fmaf(a_,w0.w,acc[ 3]);           \
    acc[ 4]=fmaf(a_,w1.x,acc[ 4]); acc[ 5]=fmaf(a_,w1.y,acc[ 5]);           \
    acc[ 6]=fmaf(a_,w1.z,acc[ 6]); acc[ 7]=fmaf(a_,w1.w,acc[ 7]);           \
    acc[ 8]=fmaf(a_,w2.x,acc[ 8]); acc[ 9]=fmaf(a_,w2.y,acc[ 9]);           \
    acc[10]=fmaf(a_,w2.z,acc[10]); acc[11]=fmaf(a_,w2.w,acc[11]);           \
    acc[12]=fmaf(a_,w3.x,acc[12]); acc[13]=fmaf(a_,w3.y,acc[13]);           \
    acc[14]=fmaf(a_,w3.z,acc[14]); acc[15]=fmaf(a_,w3.w,acc[15]); }

template<int IN, bool RELU>
__device__ __forceinline__ void layer64(const float* __restrict__ W,
                                        const float* __restrict__ Ain,
                                        float* __restrict__ Bout,
                                        int row, int jb) {
  float acc[16];
#pragma unroll
  for (int j = 0; j < 16; ++j) acc[j] = 0.0f;
  const float4* __restrict__ Arow = (const float4*)(Ain + row);
#pragma unroll 2
  for (int g = 0; g < IN/4; ++g) {
    float4 a4 = Arow[g];
    FMAC16(a4.x, W + (4*g+0)*64 + jb);
    FMAC16(a4.y, W + (4*g+1)*64 + jb);
    FMAC16(a4.z, W + (4*g+2)*64 + jb);
    FMAC16(a4.w, W + (4*g+3)*64 + jb);
  }
#pragma unroll
  for (int k = (IN & ~3); k < IN; ++k) {   // tail (c0: k=28..30)
    float a = Ain[row + k];
    FMAC16(a, W + k*64 + jb);
  }
  float4* __restrict__ Brow = (float4*)(Bout + row + jb);
#pragma unroll
  for (int c = 0; c < 4; ++c) {
    float4 v;
    v.x = RELU ? fmaxf(acc[4*c+0], 0.0f) : acc[4*c+0];
    v.y = RELU ? fmaxf(acc[4*c+1], 0.0f) : acc[4*c+1];
    v.z = RELU ? fmaxf(acc[4*c+2], 0.0f) : acc[4*c+2];
    v.w = RELU ? fmaxf(acc[4*c+3], 0.0f) : acc[4*c+3];
    Brow[c] = v;
  }
}

// IN=64 -> OUT=16 (s2, no relu). Returns acc[0] (sigma when jb4==0).
__device__ __forceinline__ float layer16(const float* __restrict__ W,
                                         const float* __restrict__ Ain,
                                         float* __restrict__ Bout,
                                         int row, int jb4) {
  float acc[4] = {0.f, 0.f, 0.f, 0.f};
  const float4* __restrict__ Arow = (const float4*)(Ain + row);
#pragma unroll 4
  for (int g = 0; g < 16; ++g) {
    float4 a4 = Arow[g];
#pragma unroll
    for (int ks = 0; ks < 4; ++ks) {
      int k = 4*g + ks;
      float a = (ks==0)?a4.x:(ks==1)?a4.y:(ks==2)?a4.z:a4.w;
      float4 w = *(const float4*)(W + k*16 + jb4);
      acc[0]=fmaf(a,w.x,acc[0]); acc[1]=fmaf(a,w.y,acc[1]);
      acc[2]=fmaf(a,w.z,acc[2]); acc[3]=fmaf(a,w.w,acc[3]);
    }
  }
  *(float4*)(Bout + row + jb4) = make_float4(acc[0],acc[1],acc[2],acc[3]);
  return acc[0];
}

// IN=64 -> OUT=3 (c3, no relu), results in registers. W laundered to vector loads.
__device__ __forceinline__ void layer3(const float* __restrict__ W,
                                       const float* __restrict__ Ain,
                                       int row, float out3[3]) {
  float a0 = 0.f, a1 = 0.f, a2 = 0.f;
  const float4* __restrict__ Arow = (const float4*)(Ain + row);
#pragma unroll 4
  for (int g = 0; g < 16; ++g) {
    float4 a4 = Arow[g];
#pragma unroll
    for (int ks = 0; ks < 4; ++ks) {
      int k = 4*g + ks;
      float a = (ks==0)?a4.x:(ks==1)?a4.y:(ks==2)?a4.z:a4.w;
      a0 = fmaf(a, W[k*3+0], a0);
      a1 = fmaf(a, W[k*3+1], a1);
      a2 = fmaf(a, W[k*3+2], a2);
    }
  }
  out3[0]=a0; out3[1]=a1; out3[2]=a2;
}

// ---------------- kernel 2: hybrid-tile MLP, barrier-free ----------------
// lane = p + 16*jg. Wave q owns points q*16..q*16+15 end-to-end (gather ->
// layers -> write): zero __syncthreads. Acts in LDS [point][feat] rows
// (ds_read_b128 = 4 k's). Weights per-lane-divergent coalesced global loads
// (vmcnt in-order pipelining; L1-hot 16KB/layer).
__global__ __launch_bounds__(MBLK)
void k_mlp(const float* __restrict__ rays,
           const float* __restrict__ tables,
           const float* __restrict__ w_s0, const float* __restrict__ w_s1,
           const float* __restrict__ w_s2, const float* __restrict__ w_c0,
           const float* __restrict__ w_c1, const float* __restrict__ w_c2,
           const float* __restrict__ w_c3,
           const float* __restrict__ sh,
           const unsigned* __restrict__ counter,
           const unsigned* __restrict__ plist,
           float4* __restrict__ results) {
  __shared__ __align__(16) float A[64*STR];
  __shared__ __align__(16) float B[64*STR];
  const int t = threadIdx.x;
  const int lane = t & 63;
  const int p    = lane & 15;
  const int jg   = lane >> 4;
  const int q    = __builtin_amdgcn_readfirstlane(t >> 6);
  const int wb   = q * 16;           // wave's point base within tile
  const int gp   = wb + p;           // this lane's point slot (0..63)
  const int row  = gp * STR;
  const int jb   = jg * 16;
  int zoff = 0; asm volatile("" : "+v"(zoff));   // launder: keep c3 W loads vector
  const float* __restrict__ w_c3v = w_c3 + zoff;
  const unsigned count = *counter;
  const unsigned ntiles = (count + 63u) >> 6;
  const float RESF[NLEV] = {16.f,20.f,25.f,32.f,40.f,50.f,64.f,80.f,
                            101.f,128.f,161.f,203.f,256.f,322.f,406.f,512.f};
  for (unsigned tile = blockIdx.x; tile < ntiles; tile += MGRID) {
    unsigned s = (tile << 6) + (unsigned)gp;
    unsigned pid = (s < count) ? plist[s] : 0u;
    int r = (int)(pid >> 7);
    int i = (int)(pid & 127u);
    // ---- hash gather: lane (p,jg) does levels 4jg..4jg+3 for point gp ----
    {
      float zi = zval32(i);
      float px = pcoord(rays[6*r+0], rays[6*r+3], zi);
      float py = pcoord(rays[6*r+1], rays[6*r+4], zi);
      float pz = pcoord(rays[6*r+2], rays[6*r+5], zi);
      float xcx = fminf(fmaxf(px, -1.5f), 1.5f);
      float xcy = fminf(fmaxf(py, -1.5f), 1.5f);
      float xcz = fminf(fmaxf(pz, -1.5f), 1.5f);
#pragma unroll
      for (int li = 0; li < 4; ++li) {
        int l = 4*jg + li;
        const float grid = 3.0f / RESF[l];
        float bfx = floorf(__fdiv_rn(__fadd_rn(xcx, 1.5f), grid));
        float bfy = floorf(__fdiv_rn(__fadd_rn(xcy, 1.5f), grid));
        float bfz = floorf(__fdiv_rn(__fadd_rn(xcz, 1.5f), grid));
        float vmx = __fadd_rn(__fmul_rn(bfx, grid), -1.5f);
        float vmy = __fadd_rn(__fmul_rn(bfy, grid), -1.5f);
        float vmz = __fadd_rn(__fmul_rn(bfz, grid), -1.5f);
        float wx = __fdiv_rn(__fsub_rn(xcx, vmx), grid);
        float wy = __fdiv_rn(__fsub_rn(xcy, vmy), grid);
        float wz = __fdiv_rn(__fsub_rn(xcz, vmz), grid);
        unsigned cx0 = (unsigned)(int)bfx, cy0 = (unsigned)(int)bfy, cz0 = (unsigned)(int)bfz;
        unsigned cx1 = cx0 + 1u, cy1 = cy0 + 1u, cz1 = cz0 + 1u;
        unsigned hy0 = cy0*2654435761u, hy1 = cy1*2654435761u;
        unsigned hz0 = cz0*805459861u,  hz1 = cz1*805459861u;
        const float2* tb = (const float2*)tables + (size_t)l*THASH;
        float2 e000 = tb[(cx0^hy0^hz0)&(THASH-1)];
        float2 e001 = tb[(cx0^hy0^hz1)&(THASH-1)];
        float2 e010 = tb[(cx0^hy1^hz0)&(THASH-1)];
        float2 e011 = tb[(cx0^hy1^hz1)&(THASH-1)];
        float2 e100 = tb[(cx1^hy0^hz0)&(THASH-1)];
        float2 e101 = tb[(cx1^hy0^hz1)&(THASH-1)];
        float2 e110 = tb[(cx1^hy1^hz0)&(THASH-1)];
        float2 e111 = tb[(cx1^hy1^hz1)&(THASH-1)];
        float iwx = 1.f-wx, iwy = 1.f-wy, iwz = 1.f-wz;
        float c00a = e000.x*iwx + e100.x*wx, c00b = e000.y*iwx + e100.y*wx;
        float c01a = e001.x*iwx + e101.x*wx, c01b = e001.y*iwx + e101.y*wx;
        float c10a = e010.x*iwx + e110.x*wx, c10b = e010.y*iwx + e110.y*wx;
        float c11a = e011.x*iwx + e111.x*wx, c11b = e011.y*iwx + e111.y*wx;
        float c0a = c00a*iwy + c10a*wy, c0b = c00b*iwy + c10b*wy;
        float c1a = c01a*iwy + c11a*wy, c1b = c01b*iwy + c11b*wy;
        float2 f2;
        f2.x = c0a*iwz + c1a*wz;
        f2.y = c0b*iwz + c1b*wz;
        *(float2*)(A + row + 2*l) = f2;
      }
    }
    // ---- sigma MLP (all per-wave-local; no barriers) ----
    layer64<32,true >(w_s0, A, B, row, jb);
    layer64<64,true >(w_s1, B, A, row, jb);
    float sigma_r = layer16(w_s2, A, B, row, jg*4);   // jg0 lanes: acc[0] = sigma
    // ---- color input: A cols 0..15 = SH(ray), 16..30 = geo (B cols 1..15) ----
    {
      const float* shp = sh + r*16;
      int k0 = jg*8, k1 = (jg==3) ? 31 : (k0+8);
      for (int k = k0; k < k1; ++k) {
        float v = (k < 16) ? shp[k] : B[row + (k-15)];
        A[row + k] = v;
      }
    }
    layer64<31,true >(w_c0, A, B, row, jb);
    layer64<64,true >(w_c1, B, A, row, jb);
    layer64<64,true >(w_c2, A, B, row, jb);
    float c3o[3];
    layer3(w_c3v, B, row, c3o);
    if (jg == 0 && s < count) {
      results[s] = make_float4(sigma_r, c3o[0], c3o[1], c3o[2]);
    }
  }
}

// ---------------- kernel 3: composite, fp32 with expm1f ----------------
__global__ __launch_bounds__(64)
void k_comp(const float* __restrict__ rays,
            const unsigned* __restrict__ rbase,
            const unsigned* __restrict__ rn,
            const float4* __restrict__ results,
            float* __restrict__ out) {
  int r = blockIdx.x * 64 + threadIdx.x;
  if (r >= NRAYS) return;
  float dx = rays[6*r+3], dy = rays[6*r+4], dz = rays[6*r+5];
  float dnorm = sqrtf(dx*dx + dy*dy + dz*dz);
  int n = (int)rn[r];
  unsigned base = rbase[r];
  const float step = 4.0f/127.0f;
  const float diststep = __fmul_rn(step, dnorm);   // n<=47<127: never the 1e10 tail
  float S = 0.f, ch0 = 0.f, ch1 = 0.f, ch2 = 0.f, dep = 0.f, trans = 1.f;
  for (int i = 0; i < n; ++i) {
    float4 rs = results[base + i];
    float z = zval32(i);
    float sg = fmaxf(rs.x, 0.f);
    float alpha = -expm1f(-__fmul_rn(sg, diststep));
    float w = __fmul_rn(alpha, trans);
    trans = __fmul_rn(trans, __fadd_rn(__fsub_rn(1.f, alpha), 1e-10f));
    float s0 = 1.f/(1.f + expf(-rs.y));
    float s1 = 1.f/(1.f + expf(-rs.z));
    float s2 = 1.f/(1.f + expf(-rs.w));
    S += w; ch0 += w*s0; ch1 += w*s1; ch2 += w*s2; dep += w*z;
  }
  float rem  = __fadd_rn(__fsub_rn(1.f, S), 1e-6f);
  float Stot = __fadd_rn(S, rem);
  float loss = 0.f, trans2 = 1.f;
  for (int i = 0; i < n; ++i) {
    float4 rs = results[base + i];
    float sg = fmaxf(rs.x, 0.f);
    float alpha = -expm1f(-__fmul_rn(sg, diststep));
    float w = __fmul_rn(alpha, trans2);
    trans2 = __fmul_rn(trans2, __fadd_rn(__fsub_rn(1.f, alpha), 1e-10f));
    float pq = __fdiv_rn(w, Stot);
    loss += pq * logf(fmaxf(pq, 1e-37f));
  }
  float pl = __fdiv_rn(rem, Stot);
  loss += pl * logf(fmaxf(pl, 1e-37f));
  out[3*r+0] = ch0; out[3*r+1] = ch1; out[3*r+2] = ch2;
  out[3*NRAYS + r] = dep;
  out[4*NRAYS + r] = -loss;
}

// ---------------- launch ----------------
extern "C" void kernel_launch(void* const* d_in, const int* in_sizes, int n_in,
                              void* d_out, int out_size, void* d_ws, size_t ws_size,
                              hipStream_t stream) {
  const float* rays   = (const float*)d_in[0];
  const float* tables = (const float*)d_in[1];
  const float* ws0    = (const float*)d_in[2];
  const float* ws1    = (const float*)d_in[3];
  const float* ws2    = (const float*)d_in[4];
  const float* wc0    = (const float*)d_in[5];
  const float* wc1    = (const float*)d_in[6];
  const float* wc2    = (const float*)d_in[7];
  const float* wc3    = (const float*)d_in[8];

  char* ws = (char*)d_ws;
  unsigned* counter = (unsigned*)ws;
  unsigned* rbase   = (unsigned*)(ws + 256);
  unsigned* rn      = (unsigned*)(ws + 256 + 65536);
  float*    sh      = (float*)  (ws + 256 + 131072);
  float4*   results = (float4*) (ws + 1179904);
  unsigned* plist   = (unsigned*)(ws + 1179904 + (size_t)MAXPTS*16);

  hipMemsetAsync(counter, 0, 4, stream);
  k_classify<<<NRAYS/64, 64, 0, stream>>>(rays, sh, counter, rbase, rn, plist);
  k_mlp<<<MGRID, MBLK, 0, stream>>>(rays, tables, ws0, ws1, ws2,
                                    wc0, wc1, wc2, wc3, sh, counter, plist, results);
  k_comp<<<NRAYS/64, 64, 0, stream>>>(rays, rbase, rn, results, (float*)d_out);
}